// Round 7
// baseline (1036.936 us; speedup 1.0000x reference)
//
#include <hip/hip_runtime.h>
#include <math.h>

#define B_ 8
#define P_ 8192
#define N_ 65536
#define K_ 16
#define EPS_ 1e-5f
#define NC_ 64                  // x columns per batch
#define NY_ 64                  // y cells per column
#define CSC 1.28f               // 64 / 50
#define SLACK 0.999999f         // under-estimate slack (covers <=4 rn roundings)

__device__ __forceinline__ int b64(float v) {
    int b = (int)(v * CSC);
    return b > 63 ? 63 : (b < 0 ? 0 : b);
}

// ============================ 2D binning ===================================
__global__ __launch_bounds__(256) void init5(int* counts, int* cursors,
                                             int* xminI, int* xmaxI,
                                             int* yminI, int* ymaxI) {
    int i = blockIdx.x * 256 + threadIdx.x;       // 32768 cells
    counts[i] = 0; cursors[i] = 0;
    xminI[i] = 0x7F7FFFFF; xmaxI[i] = 0x80000000; // non-neg floats: int order == float order
    yminI[i] = 0x7F7FFFFF; ymaxI[i] = 0x80000000;
}

__global__ __launch_bounds__(256) void count5(const float* __restrict__ vc,
                                              int* counts, int* xminI, int* xmaxI,
                                              int* yminI, int* ymaxI) {
    int q = blockIdx.x * 256 + threadIdx.x;
    float4 p = ((const float4*)vc)[q];            // [batch, x, y, z]
    int b = q >> 13;
    int e = (b << 12) + (b64(p.y) << 6) + b64(p.z);
    atomicAdd(&counts[e], 1);
    atomicMin(&xminI[e], __float_as_int(p.y));
    atomicMax(&xmaxI[e], __float_as_int(p.y));
    atomicMin(&yminI[e], __float_as_int(p.z));
    atomicMax(&ymaxI[e], __float_as_int(p.z));
}

// exclusive prefix over 4096 cells per batch (one block of 1024, 4 cells/thread)
__global__ __launch_bounds__(1024) void scan5(const int* __restrict__ counts, int* off) {
    __shared__ int sm[1024];
    int b = blockIdx.x, t = threadIdx.x;
    int base = (b << 12) + (t << 2);
    int c0 = counts[base], c1 = counts[base+1], c2 = counts[base+2], c3 = counts[base+3];
    int tot = c0 + c1 + c2 + c3;
    sm[t] = tot; __syncthreads();
    for (int s = 1; s < 1024; s <<= 1) {
        int u = sm[t]; int v = (t >= s) ? sm[t - s] : 0;
        __syncthreads(); sm[t] = u + v; __syncthreads();
    }
    int excl = sm[t] - tot;
    int ob = b * 4097 + (t << 2);
    off[ob]   = excl;
    off[ob+1] = excl + c0;
    off[ob+2] = excl + c0 + c1;
    off[ob+3] = excl + c0 + c1 + c2;
    if (t == 1023) off[b * 4097 + 4096] = sm[t];
}

// per (batch,column): y prefix-max (ylub) / suffix-min (yglb) over cells; column x-range
__global__ __launch_bounds__(256) void bounds5(const int* __restrict__ counts,
                                               const int* __restrict__ xminI, const int* __restrict__ xmaxI,
                                               const int* __restrict__ yminI, const int* __restrict__ ymaxI,
                                               float* ylub, float* yglb,
                                               float* colxmin, float* colxmax) {
    int i = blockIdx.x * 256 + threadIdx.x;
    if (i >= B_ * NC_) return;
    int b = i >> 6, c = i & 63;
    int base = (b << 12) + (c << 6);
    float run = -1e30f, cxm = -1e30f, cxn = 1e30f;
    for (int yb = 0; yb < NY_; ++yb) {
        int ct = counts[base + yb];
        float ym = ct ? __int_as_float(ymaxI[base + yb]) : -1e30f;
        run = fmaxf(run, ym);
        ylub[base + yb] = run;
        if (ct) {
            cxm = fmaxf(cxm, __int_as_float(xmaxI[base + yb]));
            cxn = fminf(cxn, __int_as_float(xminI[base + yb]));
        }
    }
    run = 1e30f;
    for (int yb = NY_ - 1; yb >= 0; --yb) {
        int ct = counts[base + yb];
        float ym = ct ? __int_as_float(yminI[base + yb]) : 1e30f;
        run = fminf(run, ym);
        yglb[base + yb] = run;
    }
    colxmax[(b << 6) + c] = cxm;
    colxmin[(b << 6) + c] = cxn;
}

// per batch: prefix-max of colxmax -> colxlub ; suffix-min of colxmin -> colxglb
__global__ void colpre(const float* __restrict__ colxmin, const float* __restrict__ colxmax,
                       float* colxlub, float* colxglb) {
    int b = threadIdx.x;
    if (b < B_) {
        float run = -1e30f;
        for (int c = 0; c < NC_; ++c) { run = fmaxf(run, colxmax[(b<<6)+c]); colxlub[(b<<6)+c] = run; }
        run = 1e30f;
        for (int c = NC_ - 1; c >= 0; --c) { run = fminf(run, colxmin[(b<<6)+c]); colxglb[(b<<6)+c] = run; }
    }
}

__global__ __launch_bounds__(256) void scatter5(const float* __restrict__ vc,
                                                const int* __restrict__ off,
                                                int* cursors, float4* pos4s) {
    int q = blockIdx.x * 256 + threadIdx.x;
    float4 p = ((const float4*)vc)[q];
    int b = q >> 13;
    int e = (b << 12) + (b64(p.y) << 6) + b64(p.z);
    int slot = off[b * 4097 + (e & 4095)] + atomicAdd(&cursors[e], 1);
    pos4s[(b << 13) + slot] = make_float4(p.y, p.z, p.w, __int_as_float(q));
}

// ============================ knn (2D-pruned, exact, pair-split) ===========
// 2 threads/query (stride-2 within every cell). Phase 1: branchless top-16
// distance network per thread; tau = pair-min of 16th (each >= tau_true).
// Cell pruning uses certified UNDER-estimates (SLACK on rn products/sums):
// prune only when lb > tau => pruned d > tau >= tau_true. Phase 2: recollect
// (d, idx) with d <= tau into LDS; leader merges pair via u64 lex network
// (exact top_k lowest-index tie-break). No block barriers anywhere.
__global__ __launch_bounds__(256) void knn5_kernel(
    const float4* __restrict__ pos4s,
    const int* __restrict__ off,
    const float* __restrict__ ylubA,
    const float* __restrict__ yglbA,
    const float* __restrict__ colxlub,
    const float* __restrict__ colxglb,
    unsigned short* __restrict__ idx_out,
    float* __restrict__ d2_out)
{
    const int tid = threadIdx.x;
    const int g   = blockIdx.x * 256 + tid;
    const int qslot = g >> 1;
    const int sub   = g & 1;
    const int bb    = qslot >> 13;
    const float4* cp = pos4s + ((size_t)bb << 13);
    const int* offb = off + bb * 4097;
    const float* yl  = ylubA + (bb << 12);
    const float* yg  = yglbA + (bb << 12);
    const float* cxl = colxlub + (bb << 6);
    const float* cxg = colxglb + (bb << 6);

    const float4 me = cp[qslot & (P_ - 1)];
    const float qx = me.x, qy = me.y, qz = me.z;
    const int q = __float_as_int(me.w);
    const int qc = b64(qx), qyb = b64(qy);

    __shared__ float2 hb[256 * 19];     // 38 KB hit buffer
    __shared__ int cnts[256];
    const int hbase = tid * 19;

    float bd[K_];
#pragma unroll
    for (int t = 0; t < K_; ++t) bd[t] = __builtin_huge_valf();

#define DIST5_(c_, d_)                                                      \
    float d_; {                                                             \
        float dx_ = __fsub_rn(qx, (c_).x);                                  \
        float dy_ = __fsub_rn(qy, (c_).y);                                  \
        float dz_ = __fsub_rn(qz, (c_).z);                                  \
        d_ = __fadd_rn(__fadd_rn(__fmul_rn(dx_,dx_), __fmul_rn(dy_,dy_)),   \
                       __fmul_rn(dz_,dz_));                                 \
    }

// unconditional 32-op network: depth-2 per candidate, no branches
#define NET5_(d_) {                                                         \
        _Pragma("unroll")                                                   \
        for (int t = K_-1; t > 0; --t)                                      \
            bd[t] = fminf(bd[t], fmaxf(bd[t-1], d_));                       \
        bd[0] = fminf(bd[0], d_);                                           \
    }

#define SCANB1(cc, yy) {                                                    \
        int bi_ = ((cc) << 6) + (yy);                                       \
        int j0_ = offb[bi_], j1_ = offb[bi_ + 1];                           \
        for (int j = j0_ + sub; j < j1_; j += 2) {                          \
            float4 c_ = cp[j];                                              \
            DIST5_(c_, d_)                                                  \
            NET5_(d_)                                                       \
        } }

#define COL1(cc, dx2u) {                                                    \
        SCANB1(cc, qyb)                                                     \
        for (int yb = qyb - 1; yb >= 0; --yb) {                             \
            float t_ = __fsub_rn(qy, yl[((cc) << 6) + yb]);                 \
            float dy2_ = t_ > 0.f ? __fmul_rn(__fmul_rn(t_,t_), SLACK) : 0.f; \
            if (__fmul_rn(__fadd_rn(dx2u, dy2_), SLACK) > tau) break;       \
            SCANB1(cc, yb)                                                  \
        }                                                                   \
        for (int yb = qyb + 1; yb < NY_; ++yb) {                            \
            float t_ = __fsub_rn(yg[((cc) << 6) + yb], qy);                 \
            float dy2_ = t_ > 0.f ? __fmul_rn(__fmul_rn(t_,t_), SLACK) : 0.f; \
            if (__fmul_rn(__fadd_rn(dx2u, dy2_), SLACK) > tau) break;       \
            SCANB1(cc, yb)                                                  \
        } }

    // ---- phase 1: home column (full scan), then column expansion ----
    {
        int j0 = offb[qc << 6], j1 = offb[(qc + 1) << 6];
        for (int j = j0 + sub; j < j1; j += 2) {
            float4 c_ = cp[j];
            DIST5_(c_, d_)
            NET5_(d_)
        }
    }
    float tau = fminf(bd[K_-1], __shfl_xor(bd[K_-1], 1));
    int cl = qc - 1, cr = qc + 1;
    for (;;) {
        bool needL = false, needR = false;
        float dxl = 0.f, dxr = 0.f;
        if (cl >= 0) {
            float t_ = __fsub_rn(qx, cxl[cl]);
            dxl = t_ > 0.f ? __fmul_rn(__fmul_rn(t_,t_), SLACK) : 0.f;
            needL = !(dxl > tau);
        }
        if (cr < NC_) {
            float t_ = __fsub_rn(cxg[cr], qx);
            dxr = t_ > 0.f ? __fmul_rn(__fmul_rn(t_,t_), SLACK) : 0.f;
            needR = !(dxr > tau);
        }
        if (!needL && !needR) break;
        if (needL) {
            COL1(cl, dxl)
            --cl;
            tau = fminf(tau, fminf(bd[K_-1], __shfl_xor(bd[K_-1], 1)));
        }
        if (needR) {
            COL1(cr, dxr)
            ++cr;
            tau = fminf(tau, fminf(bd[K_-1], __shfl_xor(bd[K_-1], 1)));
        }
    }
    tau = fminf(bd[K_-1], __shfl_xor(bd[K_-1], 1));   // final bound >= tau_true

    // ---- phase 2: collect (d, idx) with d <= tau ----
    int cnt = 0;
#define SCANB2(cc, yy) {                                                    \
        int bi_ = ((cc) << 6) + (yy);                                       \
        int j0_ = offb[bi_], j1_ = offb[bi_ + 1];                           \
        for (int j = j0_ + sub; j < j1_; j += 2) {                          \
            float4 c_ = cp[j];                                              \
            DIST5_(c_, d_)                                                  \
            if (d_ <= tau && cnt < 19) {                                    \
                hb[hbase + cnt] = make_float2(d_, c_.w);                    \
                ++cnt;                                                      \
            }                                                               \
        } }

#define COL2(cc, dx2u) {                                                    \
        SCANB2(cc, qyb)                                                     \
        for (int yb = qyb - 1; yb >= 0; --yb) {                             \
            float t_ = __fsub_rn(qy, yl[((cc) << 6) + yb]);                 \
            float dy2_ = t_ > 0.f ? __fmul_rn(__fmul_rn(t_,t_), SLACK) : 0.f; \
            if (__fmul_rn(__fadd_rn(dx2u, dy2_), SLACK) > tau) break;       \
            SCANB2(cc, yb)                                                  \
        }                                                                   \
        for (int yb = qyb + 1; yb < NY_; ++yb) {                            \
            float t_ = __fsub_rn(yg[((cc) << 6) + yb], qy);                 \
            float dy2_ = t_ > 0.f ? __fmul_rn(__fmul_rn(t_,t_), SLACK) : 0.f; \
            if (__fmul_rn(__fadd_rn(dx2u, dy2_), SLACK) > tau) break;       \
            SCANB2(cc, yb)                                                  \
        } }

    {
        int j0 = offb[qc << 6], j1 = offb[(qc + 1) << 6];
        for (int j = j0 + sub; j < j1; j += 2) {
            float4 c_ = cp[j];
            DIST5_(c_, d_)
            if (d_ <= tau && cnt < 19) {
                hb[hbase + cnt] = make_float2(d_, c_.w);
                ++cnt;
            }
        }
    }
    cl = qc - 1; cr = qc + 1;
    for (;;) {
        bool needL = false, needR = false;
        float dxl = 0.f, dxr = 0.f;
        if (cl >= 0) {
            float t_ = __fsub_rn(qx, cxl[cl]);
            dxl = t_ > 0.f ? __fmul_rn(__fmul_rn(t_,t_), SLACK) : 0.f;
            needL = !(dxl > tau);
        }
        if (cr < NC_) {
            float t_ = __fsub_rn(cxg[cr], qx);
            dxr = t_ > 0.f ? __fmul_rn(__fmul_rn(t_,t_), SLACK) : 0.f;
            needR = !(dxr > tau);
        }
        if (!needL && !needR) break;
        if (needL) { COL2(cl, dxl) --cl; }
        if (needR) { COL2(cr, dxr) ++cr; }
    }

    cnts[tid] = cnt;
    __builtin_amdgcn_wave_barrier();   // pair lanes share a wave: LDS is in program order

    if (!sub) {
        unsigned long long kk[K_];
#pragma unroll
        for (int t = 0; t < K_; ++t) kk[t] = ~0ull;
        int c0 = cnt, c1 = cnts[tid + 1];
        int pbase = (tid + 1) * 19;
        for (int j = 0; j < c0; ++j) {
            float2 e = hb[hbase + j];
            unsigned long long key = ((unsigned long long)__float_as_uint(e.x) << 32)
                                   | (unsigned)__float_as_int(e.y);
            if (key < kk[K_-1]) {
#pragma unroll
                for (int t = K_-1; t > 0; --t) {
                    unsigned long long hi = kk[t-1] > key ? kk[t-1] : key;
                    kk[t] = kk[t] < hi ? kk[t] : hi;
                }
                kk[0] = kk[0] < key ? kk[0] : key;
            }
        }
        for (int j = 0; j < c1; ++j) {
            float2 e = hb[pbase + j];
            unsigned long long key = ((unsigned long long)__float_as_uint(e.x) << 32)
                                   | (unsigned)__float_as_int(e.y);
            if (key < kk[K_-1]) {
#pragma unroll
                for (int t = K_-1; t > 0; --t) {
                    unsigned long long hi = kk[t-1] > key ? kk[t-1] : key;
                    kk[t] = kk[t] < hi ? kk[t] : hi;
                }
                kk[0] = kk[0] < key ? kk[0] : key;
            }
        }
#pragma unroll
        for (int t = 0; t < K_; ++t) {
            idx_out[(size_t)q * K_ + t] = (unsigned short)(kk[t] & 0xffffu);
            d2_out[(size_t)q * K_ + t]  = __uint_as_float((unsigned)(kk[t] >> 32));
        }
    }
#undef SCANB1
#undef SCANB2
#undef COL1
#undef COL2
#undef NET5_
#undef DIST5_
}

// ============================ edgeconv (unchanged) =========================
static __device__ inline double shfl_xor_dbl(double v, int mask) {
    long long b = __double_as_longlong(v);
    int lo = (int)(b & 0xffffffffLL);
    int hi = (int)(b >> 32);
    lo = __shfl_xor(lo, mask, 64);
    hi = __shfl_xor(hi, mask, 64);
    return __longlong_as_double(((long long)hi << 32) | (unsigned long long)(unsigned int)lo);
}

template<int CIN, int COUT, bool PHA>
__global__ __launch_bounds__(256) void edge_kernel(
    const float* __restrict__ x,
    const unsigned short* __restrict__ idx,
    const float* __restrict__ d2,
    const float* __restrict__ W,
    const float* __restrict__ bias,
    const float* __restrict__ wk,
    const float* __restrict__ wq,
    const float* __restrict__ acoef,
    const float* __restrict__ ccoef,
    double* __restrict__ gsum,
    double* __restrict__ gsumsq,
    float* __restrict__ out,
    int niter)
{
    constexpr int LOGC = (COUT == 64) ? 6 : 5;
    constexpr int GPW  = 64 / COUT;
    constexpr int GPB  = 4 * GPW;
    constexpr int C4   = CIN / 4;
    constexpr int SJ   = (K_ + 1) * CIN;
    constexpr int HTS  = COUT + 1;
    constexpr int HTN  = PHA ? 1 : (K_ * HTS);
    constexpr int PN   = PHA ? 1 : (K_ * K_);
    constexpr int KQN  = PHA ? 1 : (2 * K_);
    constexpr int SCN  = PHA ? 1 : K_;
    constexpr int PARTN= (!PHA && COUT == 64) ? 64 : 1;
    constexpr int WKQN = PHA ? 1 : (2 * COUT);

    const int tid  = threadIdx.x;
    const int wave = tid >> 6;
    const int lane = tid & 63;
    const int lo   = lane & (COUT - 1);
    const int grp  = lane >> LOGC;
    const int gidx = wave * GPW + grp;

    __shared__ __align__(16) float sj_s[GPB][SJ];
    __shared__ __align__(16) float hT_s[GPB][HTN];
    __shared__ __align__(16) float p_s[GPB][PN];
    __shared__ __align__(16) float kqv_s[GPB][KQN];
    __shared__ __align__(16) float rden_s[GPB][SCN];
    __shared__ __align__(16) float scal_s[GPB][SCN];
    __shared__ __align__(16) float part_s[GPB][PARTN];
    __shared__ __align__(16) float wkq_s[WKQN];

    float Wr[CIN], Ad[CIN];
#pragma unroll
    for (int c = 0; c < CIN; ++c) {
        float wl = W[lo * (2*CIN) + c];
        float wr = W[lo * (2*CIN) + CIN + c];
        Wr[c] = wr; Ad[c] = wl - wr;
    }
    const float b_s = bias[lo];

    float a_s = 0.f, c_s = 0.f;
    if constexpr (!PHA) {
        a_s = acoef[lo]; c_s = ccoef[lo];
        if (tid < COUT)            wkq_s[tid] = wk[tid];
        else if (tid < 2*COUT)     wkq_s[tid] = wq[tid - COUT];
    }
    __syncthreads();

    double lsum = 0.0, lsq = 0.0;
    const int g0      = blockIdx.x * GPB + gidx;
    const int gstride = gridDim.x * GPB;

    for (int it = 0; it < niter; ++it) {
        const int n = g0 + it * gstride;

        {
            const float4* xs  = (const float4*)x;
            float4*       sj4 = (float4*)sj_s[gidx];
            constexpr int TOT4 = (K_ + 1) * C4;
#pragma unroll
            for (int e0 = 0; e0 < TOT4; e0 += COUT) {
                int e = e0 + lo;
                if (e < TOT4) {
                    int r = e / C4;
                    int c = e - r * C4;
                    int row = (r < K_) ? (int)idx[n * K_ + r] : n;
                    sj4[e] = xs[row * C4 + c];
                }
            }
        }
        if constexpr (!PHA) {
            if (lo < K_) {
                float dis = sqrtf(d2[n * K_ + lo]);
                float e = __expf(-dis);
                scal_s[gidx][lo] = 2.0f * e / (1.0f + e);
            }
        }
        __syncthreads();

        const float* sj = sj_s[gidx];
        float t0 = b_s;
#pragma unroll
        for (int c = 0; c < C4; ++c) {
            float4 v = ((const float4*)(sj + K_ * CIN))[c];
            t0 = fmaf(Ad[4*c  ], v.x, t0);
            t0 = fmaf(Ad[4*c+1], v.y, t0);
            t0 = fmaf(Ad[4*c+2], v.z, t0);
            t0 = fmaf(Ad[4*c+3], v.w, t0);
        }
        float hn[K_];
#pragma unroll
        for (int k = 0; k < K_; ++k) {
            float acc = t0;
            const float4* xr = (const float4*)(sj + k * CIN);
#pragma unroll
            for (int c = 0; c < C4; ++c) {
                float4 v = xr[c];
                acc = fmaf(Wr[4*c  ], v.x, acc);
                acc = fmaf(Wr[4*c+1], v.y, acc);
                acc = fmaf(Wr[4*c+2], v.z, acc);
                acc = fmaf(Wr[4*c+3], v.w, acc);
            }
            float h = fmaxf(acc, 0.f);
            if constexpr (PHA) {
                double hd = (double)h;
                lsum += hd;
                lsq  = fma(hd, hd, lsq);
            } else {
                hn[k] = fmaf(a_s, h, c_s);
            }
        }

        if constexpr (!PHA) {
            float* hT = hT_s[gidx];
#pragma unroll
            for (int k = 0; k < K_; ++k) hT[k * HTS + lo] = hn[k];
            __syncthreads();

            const int kk   = lo & 15;
            const int role = lo >> 4;
            float av = 0.f;
            const float* hrow = hT + kk * HTS;
            int obase; const float* wv;
            if constexpr (COUT == 64) { obase = (role & 1) * 32; wv = wkq_s + ((role >> 1) ? COUT : 0); }
            else                      { obase = 0;               wv = wkq_s + (role ? COUT : 0); }
#pragma unroll
            for (int j = 0; j < 32; ++j)
                av = fmaf(hrow[obase + j], wv[obase + j], av);
            if constexpr (COUT == 64) {
                part_s[gidx][lo] = av;
                __syncthreads();
                if (lo < 16)      kqv_s[gidx][lo] = part_s[gidx][lo]      + part_s[gidx][lo + 16];
                else if (lo < 32) kqv_s[gidx][lo] = part_s[gidx][lo + 16] + part_s[gidx][lo + 32];
            } else {
                kqv_s[gidx][lo] = av;
            }
            __syncthreads();

            if (lo < K_) {
                const int qq = lo;
                const float qv = kqv_s[gidx][K_ + qq];
                float m = -__builtin_huge_valf();
#pragma unroll
                for (int k = 0; k < K_; ++k) m = fmaxf(m, kqv_s[gidx][k] * qv);
                float den = 0.f;
#pragma unroll
                for (int k = 0; k < K_; ++k) {
                    float e = __expf(kqv_s[gidx][k] * qv - m);
                    den += e;
                    p_s[gidx][k * K_ + qq] = e;
                }
                rden_s[gidx][qq] = 1.0f / den;
            }
            __syncthreads();

            float hq[K_];
#pragma unroll
            for (int qq = 0; qq < K_; ++qq) hq[qq] = 0.f;
#pragma unroll
            for (int k = 0; k < K_; ++k) {
                const float hnk = hn[k];
                const float4* p4 = (const float4*)(p_s[gidx] + k * K_);
#pragma unroll
                for (int j = 0; j < 4; ++j) {
                    float4 v = p4[j];
                    hq[4*j  ] = fmaf(hnk, v.x, hq[4*j  ]);
                    hq[4*j+1] = fmaf(hnk, v.y, hq[4*j+1]);
                    hq[4*j+2] = fmaf(hnk, v.z, hq[4*j+2]);
                    hq[4*j+3] = fmaf(hnk, v.w, hq[4*j+3]);
                }
            }
            float res = -__builtin_huge_valf();
#pragma unroll
            for (int j = 0; j < 4; ++j) {
                float4 sc = ((const float4*)scal_s[gidx])[j];
                float4 rd = ((const float4*)rden_s[gidx])[j];
                res = fmaxf(res, sc.x * (hq[4*j  ] * rd.x));
                res = fmaxf(res, sc.y * (hq[4*j+1] * rd.y));
                res = fmaxf(res, sc.z * (hq[4*j+2] * rd.z));
                res = fmaxf(res, sc.w * (hq[4*j+3] * rd.w));
            }
            out[n * COUT + lo] = res;
            __syncthreads();
        } else {
            __syncthreads();
        }
    }

    if constexpr (PHA) {
        if constexpr (COUT == 32) {
            lsum += shfl_xor_dbl(lsum, 32);
            lsq  += shfl_xor_dbl(lsq, 32);
        }
        __shared__ double redS[4][COUT];
        __shared__ double redQ[4][COUT];
        if (lane < COUT) { redS[wave][lane] = lsum; redQ[wave][lane] = lsq; }
        __syncthreads();
        if (tid < COUT) {
            double ss = redS[0][tid] + redS[1][tid] + redS[2][tid] + redS[3][tid];
            double qq = redQ[0][tid] + redQ[1][tid] + redQ[2][tid] + redQ[3][tid];
            atomicAdd(&gsum[tid], ss);
            atomicAdd(&gsumsq[tid], qq);
        }
    }
}

__global__ void finalize_kernel(const double* __restrict__ gsum, const double* __restrict__ gsumsq,
                                const float* __restrict__ gamma, const float* __restrict__ beta,
                                float* __restrict__ a, float* __restrict__ c, int cout)
{
    int o = threadIdx.x;
    if (o < cout) {
        const double inv = 1.0 / ((double)N_ * (double)K_);
        double mu  = gsum[o] * inv;
        double var = gsumsq[o] * inv - mu * mu;
        double rs  = 1.0 / sqrt(var + (double)EPS_);
        double av  = rs * (double)gamma[o];
        a[o] = (float)av;
        c[o] = (float)((double)beta[o] - mu * av);
    }
}

__global__ __launch_bounds__(256) void copy_vc(const float4* __restrict__ src,
                                               float4* __restrict__ dst) {
    int i = blockIdx.x * 256 + threadIdx.x;
    dst[i] = src[i];
}

extern "C" void kernel_launch(void* const* d_in, const int* in_sizes, int n_in,
                              void* d_out, int out_size, void* d_ws, size_t ws_size,
                              hipStream_t stream)
{
    const float* pillar = (const float*)d_in[0];
    const float* vc     = (const float*)d_in[1];
    const float* W0  = (const float*)d_in[2];
    const float* b0  = (const float*)d_in[3];
    const float* g0  = (const float*)d_in[4];
    const float* be0 = (const float*)d_in[5];
    const float* wk0 = (const float*)d_in[6];
    const float* wq0 = (const float*)d_in[7];
    const float* W1  = (const float*)d_in[8];
    const float* b1  = (const float*)d_in[9];
    const float* g1  = (const float*)d_in[10];
    const float* be1 = (const float*)d_in[11];
    const float* wk1 = (const float*)d_in[12];
    const float* wq1 = (const float*)d_in[13];

    // ---- workspace (< 16 MiB total) ----
    char* ws = (char*)d_ws;
    double* dsum = (double*)ws;                              // 2 KB @ 0
    double *s0 = dsum, *sq0 = dsum + 64, *s1 = dsum + 128, *sq1 = dsum + 192;
    float* coef = (float*)(ws + 4096);                       // 1 KB @ 4K
    float *a0 = coef, *c0 = coef + 64, *a1 = coef + 128, *c1 = coef + 192;
    unsigned short* idx = (unsigned short*)(ws + 8192);      // 2 MB
    float* d2  = (float*)(ws + 8192 + (size_t)N_*K_*2);      // 4 MB
    float* x1  = (float*)(ws + 8192 + (size_t)N_*K_*6);      // 8 MB
    size_t base2 = 8192 + (size_t)N_*K_*6 + (size_t)N_*32*4; // = 14 MB + 8 KB
    float4* pos4s = (float4*)(ws + base2);                   // 1 MB
    char* p2 = ws + base2 + (1u << 20);
    const size_t NB2 = (size_t)B_ * 4096;                    // 32768 cells
    int* counts  = (int*)p2;  p2 += NB2 * 4;                 // 128 KB
    int* cursors = (int*)p2;  p2 += NB2 * 4;
    int* off     = (int*)p2;  p2 += (size_t)B_ * 4097 * 4;   // ~128 KB
    int* xminI   = (int*)p2;  p2 += NB2 * 4;
    int* xmaxI   = (int*)p2;  p2 += NB2 * 4;
    int* yminI   = (int*)p2;  p2 += NB2 * 4;
    int* ymaxI   = (int*)p2;  p2 += NB2 * 4;
    float* ylubA = (float*)p2; p2 += NB2 * 4;
    float* yglbA = (float*)p2; p2 += NB2 * 4;
    float* colxmin = (float*)p2; p2 += B_ * NC_ * 4;
    float* colxmax = (float*)p2; p2 += B_ * NC_ * 4;
    float* colxlub = (float*)p2; p2 += B_ * NC_ * 4;
    float* colxglb = (float*)p2; p2 += B_ * NC_ * 4;

    float* xout = (float*)d_out;
    float* vout = xout + (size_t)N_ * 64;

    hipMemsetAsync(dsum, 0, 2048, stream);
    init5<<<NB2 / 256, 256, 0, stream>>>(counts, cursors, xminI, xmaxI, yminI, ymaxI);
    count5<<<N_ / 256, 256, 0, stream>>>(vc, counts, xminI, xmaxI, yminI, ymaxI);
    scan5<<<B_, 1024, 0, stream>>>(counts, off);
    bounds5<<<2, 256, 0, stream>>>(counts, xminI, xmaxI, yminI, ymaxI,
                                   ylubA, yglbA, colxmin, colxmax);
    colpre<<<1, 64, 0, stream>>>(colxmin, colxmax, colxlub, colxglb);
    scatter5<<<N_ / 256, 256, 0, stream>>>(vc, off, cursors, pos4s);
    knn5_kernel<<<N_ * 2 / 256, 256, 0, stream>>>(pos4s, off, ylubA, yglbA,
                                                  colxlub, colxglb, idx, d2);

    edge_kernel<4,32,true ><<<1024, 256, 0, stream>>>(pillar, idx, d2, W0, b0, wk0, wq0,
                                                      nullptr, nullptr, s0, sq0, nullptr, 8);
    finalize_kernel<<<1, 64, 0, stream>>>(s0, sq0, g0, be0, a0, c0, 32);
    edge_kernel<4,32,false><<<1024, 256, 0, stream>>>(pillar, idx, d2, W0, b0, wk0, wq0,
                                                      a0, c0, nullptr, nullptr, x1, 8);

    edge_kernel<32,64,true ><<<2048, 256, 0, stream>>>(x1, idx, d2, W1, b1, wk1, wq1,
                                                       nullptr, nullptr, s1, sq1, nullptr, 8);
    finalize_kernel<<<1, 64, 0, stream>>>(s1, sq1, g1, be1, a1, c1, 64);
    edge_kernel<32,64,false><<<2048, 256, 0, stream>>>(x1, idx, d2, W1, b1, wk1, wq1,
                                                       a1, c1, nullptr, nullptr, xout, 8);

    copy_vc<<<256, 256, 0, stream>>>((const float4*)vc, (float4*)vout);
}